// Round 10
// baseline (217.260 us; speedup 1.0000x reference)
//
#include <hip/hip_runtime.h>

#define TT 512
#define BB 1024
#define FF 16
#define HH 32
#define OO 8
#define CH 16             // timesteps per x-chunk
#define NC (TT / CH)      // 32 chunks
#define NG 128            // gate rows (4*HH)

typedef _Float16 f16;
typedef f16 v4h __attribute__((ext_vector_type(4)));
typedef f16 v8h __attribute__((ext_vector_type(8)));
typedef float f32x4 __attribute__((ext_vector_type(4)));

__device__ __forceinline__ float rcp_fast(float x) { return __builtin_amdgcn_rcpf(x); }
// inputs PRE-SCALED by log2e (resp. 2*log2e) -> plain exp2
__device__ __forceinline__ float sigm2(float y) {
    return rcp_fast(1.0f + __builtin_amdgcn_exp2f(-y));
}

// One wave per block, one sequence per wave (2048 blocks, 2 waves/SIMD).
// BOTH matvecs on the matrix pipe:
//  - x-part: batched per 16-step chunk (8 MFMA, cols=steps), scattered to
//    LDS gxb[step][gate] with XOR swizzle (r9, validated).
//  - h-part: per step, 8x mfma_f32_16x16x32_f16 (K=32=H exactly); B = h
//    broadcast to all 16 cols from a 64B LDS buffer (1 ds_read_b128).
// D layout (col=lane&15, row=4*(lane>>4)+reg) puts gates i/f/g/o of unit
// u = 4*(lane>>4)+(lane&3)+16*((lane>>3)&1) at the SAME (row,reg) of tiles
// {kh,2+kh,4+kh,6+kh} -> each lane activates its own unit from its own acc
// regs (28-cndmask reg/kh select). Lane bit 2 = redundant copy; both keep
// c,h (no cross-lane exchange at all). Per-step VALU: extract+act only.
__global__ __launch_bounds__(64, 2)
void lstm_seq_kernel(const float* __restrict__ x,
                     const float* __restrict__ Wih_f, const float* __restrict__ Whh_f,
                     const float* __restrict__ b_f,
                     const float* __restrict__ Wih_b, const float* __restrict__ Whh_b,
                     const float* __restrict__ b_b,
                     float* __restrict__ hidden)
{
    const int bid  = blockIdx.x;          // 0..2047
    const int dir  = bid >> 10;           // 0 = fwd, 1 = bwd
    const int bb   = bid & (BB - 1);      // batch row
    const int lane = threadIdx.x;

    // unit ownership
    const int  rsel  = lane & 3;           // acc reg index (runtime)
    const int  kh    = (lane >> 3) & 1;    // tile parity (u bit 4)
    const int  grp   = lane >> 4;          // row group 0..3
    const int  u     = 4 * grp + rsel + 16 * kh;   // hidden unit 0..31
    const bool owner = ((lane & 4) == 0);  // one of 2 redundant lanes

    const float* __restrict__ Wih  = dir ? Wih_b : Wih_f;
    const float* __restrict__ Whh  = dir ? Whh_b : Whh_f;
    const float* __restrict__ bias = dir ? b_b   : b_f;

    const float LOG2E = 1.4426950408889634f;
    const float L2E2  = 2.0f * LOG2E;

    // ---- A fragments for the h-MFMA: tile T rows = gates 16T+(lane&15) ----
    v8h awh[8];
#pragma unroll
    for (int T = 0; T < 8; ++T) {
        const float sc = (T == 4 || T == 5) ? L2E2 : LOG2E;  // g-gates x2log2e
        const float* wrow = Whh + (T * 16 + (lane & 15)) * HH + grp * 8;
        v8h t;
#pragma unroll
        for (int j = 0; j < 8; ++j) t[j] = (f16)(wrow[j] * sc);
        awh[T] = t;
    }

    // ---- A fragments for the x-MFMA (r9, validated): k padded 16->32 ----
    v8h awx[8];
#pragma unroll
    for (int T = 0; T < 8; ++T) {
        v8h t = {(f16)0,(f16)0,(f16)0,(f16)0,(f16)0,(f16)0,(f16)0,(f16)0};
        if (lane < 32) {
            const int gate = T * 16 + (lane & 15);
            const float sc = (gate >= 64 && gate < 96) ? L2E2 : LOG2E;
            const float* wrow = Wih + gate * FF + (lane >> 4) * 8;
#pragma unroll
            for (int j = 0; j < 8; ++j) t[j] = (f16)(wrow[j] * sc);
        }
        awx[T] = t;
    }

    // ---- this lane's unit biases (pre-scaled) ----
    float pb[4];
#pragma unroll
    for (int cc = 0; cc < 4; ++cc)
        pb[cc] = bias[u + 32 * cc] * ((cc == 2) ? L2E2 : LOG2E);

    __shared__ __align__(16) f16   xsb[2 * CH * FF];   // 1 KB: x chunks (f16)
    __shared__ __align__(16) float gxb[2 * CH * NG];   // 16 KB: x-gates (f32)
    __shared__ __align__(16) f16   hbuf[HH];           // 64 B: h broadcast

    // ---- x chunk staging: lane (sl,wl) covers step sl, quarter wl ----
    const int sl = lane >> 2;
    const int wl = lane & 3;
    const int t0 = dir ? (TT - 1 - sl) : sl;
    const float* xp = x + (size_t)t0 * (BB * FF) + (size_t)bb * FF + wl * 4;
    const ptrdiff_t dstep = (dir ? -(ptrdiff_t)CH : (ptrdiff_t)CH) * (BB * FF);

    // MFMA scatter base for gx: col (lane&15)=step, row (lane>>4)*4+reg=gate
    const int mst = lane & 15;
    const int mq  = (lane >> 4) * 4;
    const int mxr = (mst & 7) << 2;

    // prologue: stage chunk 0, compute gx[0], prefetch chunk 1, init h
    {
        float4 f0 = *(const float4*)xp;
        *(v4h*)(xsb + sl * FF + wl * 4) =
            (v4h){(f16)f0.x, (f16)f0.y, (f16)f0.z, (f16)f0.w};
    }
    xp += dstep;
    if (lane < HH) hbuf[lane] = (f16)0.0f;
    __syncthreads();
    {
        v8h bx = {(f16)0,(f16)0,(f16)0,(f16)0,(f16)0,(f16)0,(f16)0,(f16)0};
        if (lane < 32)
            bx = *(const v8h*)(xsb + (lane & 15) * FF + (lane >> 4) * 8);
        float* gw = gxb + mst * NG;
#pragma unroll
        for (int T = 0; T < 8; ++T) {
            f32x4 acc = __builtin_amdgcn_mfma_f32_16x16x32_f16(
                awx[T], bx, (f32x4){0.f, 0.f, 0.f, 0.f}, 0, 0, 0);
            *(f32x4*)(gw + ((mq + T * 16) ^ mxr)) = acc;
        }
    }
    float4 nf = *(const float4*)xp;   // chunk 1
    xp += dstep;
    __syncthreads();

    float c = 0.0f, h = 0.0f;

    for (int ci = 0; ci < NC; ++ci) {
        const int bufc = ci & 1;
        if (ci + 1 < NC) {
            const int bufn = bufc ^ 1;
            // stage chunk ci+1 and compute its gx (off the critical chain)
            *(v4h*)(xsb + bufn * (CH * FF) + sl * FF + wl * 4) =
                (v4h){(f16)nf.x, (f16)nf.y, (f16)nf.z, (f16)nf.w};
            v8h bx = {(f16)0,(f16)0,(f16)0,(f16)0,(f16)0,(f16)0,(f16)0,(f16)0};
            if (lane < 32)
                bx = *(const v8h*)(xsb + bufn * (CH * FF) + (lane & 15) * FF + (lane >> 4) * 8);
            float* gw = gxb + bufn * (CH * NG) + mst * NG;
#pragma unroll
            for (int T = 0; T < 8; ++T) {
                f32x4 acc = __builtin_amdgcn_mfma_f32_16x16x32_f16(
                    awx[T], bx, (f32x4){0.f, 0.f, 0.f, 0.f}, 0, 0, 0);
                *(f32x4*)(gw + ((mq + T * 16) ^ mxr)) = acc;
            }
            if (ci + 2 < NC) { nf = *(const float4*)xp; xp += dstep; }
        }

        const float* gxc = gxb + bufc * (CH * NG);
#pragma unroll
        for (int tt = 0; tt < CH; ++tt) {
            // B operand: h broadcast (in-order after prev step's hbuf write)
            const v8h bh = *(const v8h*)(hbuf + grp * 8);

            // 8 h-MFMAs: gates = Whh_sc * h (all 16 cols identical)
            f32x4 acc[8];
#pragma unroll
            for (int T = 0; T < 8; ++T)
                acc[T] = __builtin_amdgcn_mfma_f32_16x16x32_f16(
                    awh[T], bh, (f32x4){0.f, 0.f, 0.f, 0.f}, 0, 0, 0);

            // gx + bias for this lane's unit (independent of the MFMAs)
            const int xm = (tt & 7) << 2;
            float gb[4];
#pragma unroll
            for (int cc = 0; cc < 4; ++cc)
                gb[cc] = gxc[tt * NG + ((u + 32 * cc) ^ xm)] + pb[cc];

            // extract this unit's 4 gates: reg (lane&3) within tile 2c+kh
            float e[4];
#pragma unroll
            for (int cc = 0; cc < 4; ++cc) {
                const f32x4 ta = acc[2 * cc];
                const f32x4 tb = acc[2 * cc + 1];
                const float a0 = (lane & 2) ? ((lane & 1) ? ta[3] : ta[2])
                                            : ((lane & 1) ? ta[1] : ta[0]);
                const float a1 = (lane & 2) ? ((lane & 1) ? tb[3] : tb[2])
                                            : ((lane & 1) ? tb[1] : tb[0]);
                e[cc] = kh ? a1 : a0;
            }

            const float gi = e[0] + gb[0];
            const float gf = e[1] + gb[1];
            const float gg = e[2] + gb[2];
            const float go = e[3] + gb[3];

            const float si = sigm2(gi);
            const float sf = sigm2(gf);
            const float tg = fmaf(2.0f, sigm2(gg), -1.0f);   // tanh(g)
            const float so = sigm2(go);
            c = fmaf(sf, c, si * tg);
            const float th = fmaf(2.0f, sigm2(L2E2 * c), -1.0f);  // tanh(c)
            h = so * th;

            // publish h for next step (one writer per unit)
            if (owner) hbuf[u] = (f16)h;
        }
        __syncthreads();   // 1-wave block: orders LDS buffers across chunks
    }

    if (owner) hidden[(size_t)bb * 64 + dir * HH + u] = h;
}

// FC1 + per-block partial of FC2. Grid: 32 blocks x 256 threads.
__global__ __launch_bounds__(256)
void fc_partial_kernel(const float* __restrict__ hidden,
                       const float* __restrict__ Wfh, const float* __restrict__ bfh,
                       const float* __restrict__ Wfo,
                       float* __restrict__ partials)
{
    __shared__ float wsh[OO * 64];
    const int tid = threadIdx.x;
    for (int i = tid; i < OO * 64; i += 256) wsh[i] = Wfh[i];
    __syncthreads();

    const int r   = tid >> 3;
    const int o   = tid & 7;
    const int row = blockIdx.x * 32 + r;

    const float* hrow = hidden + (size_t)row * 64;
    float acc = bfh[o];
#pragma unroll
    for (int j = 0; j < 64; ++j) acc += hrow[j] * wsh[o * 64 + j];

    const int fidx = blockIdx.x * 256 + tid;

    float pv[OO];
#pragma unroll
    for (int o2 = 0; o2 < OO; ++o2) pv[o2] = Wfo[(size_t)o2 * (BB * OO) + fidx] * acc;

    __shared__ float red[4][OO];
#pragma unroll
    for (int o2 = 0; o2 < OO; ++o2) {
        float v = pv[o2];
        for (int off = 32; off > 0; off >>= 1) v += __shfl_down(v, off);
        if ((tid & 63) == 0) red[tid >> 6][o2] = v;
    }
    __syncthreads();
    if (tid < OO) {
        partials[blockIdx.x * OO + tid] =
            red[0][tid] + red[1][tid] + red[2][tid] + red[3][tid];
    }
}

__global__ void finalize_kernel(const float* __restrict__ partials,
                                const float* __restrict__ bfo,
                                float* __restrict__ out)
{
    __shared__ float s[OO];
    const int tid = threadIdx.x;
    if (tid < OO) {
        float acc = bfo[tid];
        for (int b = 0; b < 32; ++b) acc += partials[b * OO + tid];
        s[tid] = acc;
    }
    __syncthreads();
    if (tid == 0) {
        float m = s[0];
        for (int i = 1; i < OO; ++i) m = fmaxf(m, s[i]);
        float e[OO], sum = 0.0f;
        for (int i = 0; i < OO; ++i) { e[i] = expf(s[i] - m); sum += e[i]; }
        for (int i = 0; i < OO; ++i) out[i] = e[i] / sum;
    }
}

extern "C" void kernel_launch(void* const* d_in, const int* in_sizes, int n_in,
                              void* d_out, int out_size, void* d_ws, size_t ws_size,
                              hipStream_t stream) {
    const float* x     = (const float*)d_in[0];
    const float* Wih_f = (const float*)d_in[1];
    const float* Whh_f = (const float*)d_in[2];
    const float* b_f   = (const float*)d_in[3];
    const float* Wih_b = (const float*)d_in[4];
    const float* Whh_b = (const float*)d_in[5];
    const float* b_b   = (const float*)d_in[6];
    const float* Wfh   = (const float*)d_in[7];
    const float* bfh   = (const float*)d_in[8];
    const float* Wfo   = (const float*)d_in[9];
    const float* bfo   = (const float*)d_in[10];

    float* hidden   = (float*)d_ws;
    float* partials = hidden + (size_t)BB * 64;

    lstm_seq_kernel<<<2 * BB, 64, 0, stream>>>(x, Wih_f, Whh_f, b_f,
                                               Wih_b, Whh_b, b_b, hidden);
    fc_partial_kernel<<<32, 256, 0, stream>>>(hidden, Wfh, bfh, Wfo, partials);
    finalize_kernel<<<1, 64, 0, stream>>>(partials, bfo, (float*)d_out);
}

// Round 11
// 178.683 us; speedup vs baseline: 1.2159x; 1.2159x over previous
//
#include <hip/hip_runtime.h>

#define TT 512
#define BB 1024
#define FF 16
#define HH 32
#define OO 8
#define CH 16             // timesteps per x-chunk
#define NC (TT / CH)      // 32 chunks
#define NG 128            // gate rows (4*HH)

typedef _Float16 f16;
typedef f16 v2h __attribute__((ext_vector_type(2)));
typedef f16 v4h __attribute__((ext_vector_type(4)));
typedef f16 v8h __attribute__((ext_vector_type(8)));
typedef float f32x4 __attribute__((ext_vector_type(4)));
typedef int   v2i  __attribute__((ext_vector_type(2)));

__device__ __forceinline__ float rcp_fast(float x) { return __builtin_amdgcn_rcpf(x); }
// inputs PRE-SCALED by log2e (resp. 2*log2e) -> plain exp2
__device__ __forceinline__ float sigm2(float y) {
    return rcp_fast(1.0f + __builtin_amdgcn_exp2f(-y));
}
__device__ __forceinline__ float fdot2(v2h a, v2h b, float c) {
    return __builtin_amdgcn_fdot2(a, b, c, false);
}
__device__ __forceinline__ v2h i2h(int s) { return __builtin_bit_cast(v2h, s); }

// cross-half exchange WITHOUT a DS op: v_permlane32_swap_b32 (gfx950 VALU).
// swap(p,p): result0's hi half = p's lo half -> hi lanes see prod[lane-32].
__device__ __forceinline__ float xhalf_swap(float v) {
#if __has_builtin(__builtin_amdgcn_permlane32_swap)
    int pi = __float_as_int(v);
    v2i sw = __builtin_amdgcn_permlane32_swap(pi, pi, false, false);
    return __int_as_float(sw.x);
#else
    return __shfl_xor(v, 32);
#endif
}

// one LSTM timestep (r9-validated math). tt must be a compile-time constant
// so the gx swizzle mask and ds_read offsets fold.
#define LSTEP(tt)                                                              \
  {                                                                            \
    const int xm = ((tt) & 7) << 2;                                            \
    const float gx0 = gxc[(tt) * NG + (r0 ^ xm)];                              \
    const float gx1 = gxc[(tt) * NG + (r1 ^ xm)];                              \
    float B0 = fdot2(i2h(hs[0]), w0h[0], pb0);                                 \
    float B1 = fdot2(i2h(hs[0]), w1h[0], pb1);                                 \
    float C0 = fdot2(i2h(hs[8]), w0h[8], gx0);                                 \
    float C1 = fdot2(i2h(hs[8]), w1h[8], gx1);                                 \
    _Pragma("unroll")                                                          \
    for (int j = 1; j < 8; ++j) {                                              \
      B0 = fdot2(i2h(hs[j]),     w0h[j],     B0);                              \
      B1 = fdot2(i2h(hs[j]),     w1h[j],     B1);                              \
      C0 = fdot2(i2h(hs[8 + j]), w0h[8 + j], C0);                              \
      C1 = fdot2(i2h(hs[8 + j]), w1h[8 + j], C1);                              \
    }                                                                          \
    const float g0 = B0 + C0;                                                  \
    const float g1 = B1 + C1;                                                  \
    const float s0 = sigm2(g0);                /* si (lo) / sf (hi) */         \
    const float s1 = fmaf(sigm2(g1), pm, pa);  /* tg (lo) / so (hi) */         \
    const float prod = s0 * s1;                                                \
    const float recv = xhalf_swap(prod);                                       \
    c = fmaf(s0, c, recv);                     /* hi: sf*c + si*tg */          \
    const float th = fmaf(2.0f, sigm2(L2E2 * c), -1.0f);                       \
    h = s1 * th;                               /* hi: so*tanh(c) */            \
    const int hn = __builtin_amdgcn_mov_dpp(__float_as_int(h),                 \
                                            0xB1, 0xF, 0xF, true);             \
    auto pk = __builtin_amdgcn_cvt_pkrtz(h, __int_as_float(hn));               \
    const int pki = __builtin_bit_cast(int, pk);                               \
    _Pragma("unroll")                                                          \
    for (int m = 0; m < HH / 2; ++m)                                           \
      hs[m] = __builtin_amdgcn_readlane(pki, 32 + 2 * m);                      \
  }

// One wave per block, one sequence per wave (2048 blocks, 2 waves/SIMD).
// Row-split full-k (r9): lane (hi,kk) owns gate rows r0=kk+hi*32 (i/f),
// r1=r0+64 (g/o); h-part = 32 v_dot2 vs SGPR-broadcast h; x-part batched
// per 16-step chunk on the matrix pipe -> LDS gxb (XOR-swizzled).
// NEW vs r9 (in-order-DS scheduling):
//  - NO __syncthreads() anywhere: single-wave block, DS executes in-order,
//    so the per-chunk barrier (with its vmcnt(0)+lgkmcnt(0) drain that
//    collapsed the global prefetch) is pure overhead.
//  - staging split: {xsb write, bx read, global prefetch} at chunk top;
//    the 8 MFMA + gxb writes DEFERRED to after step 11 so steps 0..11's
//    gx reads don't queue behind the staging write train.
__global__ __launch_bounds__(64, 2)
void lstm_seq_kernel(const float* __restrict__ x,
                     const float* __restrict__ Wih_f, const float* __restrict__ Whh_f,
                     const float* __restrict__ b_f,
                     const float* __restrict__ Wih_b, const float* __restrict__ Whh_b,
                     const float* __restrict__ b_b,
                     float* __restrict__ hidden)
{
    const int bid  = blockIdx.x;          // 0..2047
    const int dir  = bid >> 10;           // 0 = fwd, 1 = bwd
    const int bb   = bid & (BB - 1);      // batch row
    const int lane = threadIdx.x;
    const int hi   = lane >> 5;           // 0: rows {i,g}   1: rows {f,o}
    const int kk   = lane & 31;

    const float* __restrict__ Wih  = dir ? Wih_b : Wih_f;
    const float* __restrict__ Whh  = dir ? Whh_b : Whh_f;
    const float* __restrict__ bias = dir ? b_b   : b_f;

    const float LOG2E = 1.4426950408889634f;
    const float L2E2  = 2.0f * LOG2E;

    const int r0 = kk + hi * HH;      // i (hi=0) / f (hi=1)
    const int r1 = r0 + 2 * HH;       // g (hi=0) / o (hi=1)
    const float sc0 = LOG2E;
    const float sc1 = hi ? LOG2E : L2E2;
    const float pm = hi ? 1.0f : 2.0f;
    const float pa = hi ? 0.0f : -1.0f;

    // ---- recurrent weights: 2 rows x 16 h-pairs, f16, pre-scaled ----
    v2h w0h[HH / 2], w1h[HH / 2];
#pragma unroll
    for (int q = 0; q < HH / 4; ++q) {
        float4 a = ((const float4*)(Whh + r0 * HH))[q];
        w0h[2*q]   = (v2h){(f16)(a.x * sc0), (f16)(a.y * sc0)};
        w0h[2*q+1] = (v2h){(f16)(a.z * sc0), (f16)(a.w * sc0)};
        float4 b2 = ((const float4*)(Whh + r1 * HH))[q];
        w1h[2*q]   = (v2h){(f16)(b2.x * sc1), (f16)(b2.y * sc1)};
        w1h[2*q+1] = (v2h){(f16)(b2.z * sc1), (f16)(b2.w * sc1)};
    }
    const float pb0 = bias[r0] * sc0;
    const float pb1 = bias[r1] * sc1;

    // ---- MFMA A-fragments for the x-GEMM (validated r8/r9) ----
    v8h awx[8];
#pragma unroll
    for (int T = 0; T < 8; ++T) {
        v8h t = {(f16)0,(f16)0,(f16)0,(f16)0,(f16)0,(f16)0,(f16)0,(f16)0};
        if (lane < 32) {
            const int gate = T * 16 + (lane & 15);
            const float sc = (gate >= 64 && gate < 96) ? L2E2 : LOG2E;
            const float* wrow = Wih + gate * FF + (lane >> 4) * 8;
#pragma unroll
            for (int j = 0; j < 8; ++j) t[j] = (f16)(wrow[j] * sc);
        }
        awx[T] = t;
    }

    __shared__ __align__(16) f16   xsb[2 * CH * FF];   // 1 KB: x chunks (f16)
    __shared__ __align__(16) float gxb[2 * CH * NG];   // 16 KB: x-gates (f32)

    // ---- x chunk staging: lane (sl,wl) covers step sl, quarter wl ----
    const int sl = lane >> 2;
    const int wl = lane & 3;
    const int t0 = dir ? (TT - 1 - sl) : sl;
    const float* xp = x + (size_t)t0 * (BB * FF) + (size_t)bb * FF + wl * 4;
    const ptrdiff_t dstep = (dir ? -(ptrdiff_t)CH : (ptrdiff_t)CH) * (BB * FF);

    // MFMA scatter base for gx: col (lane&15)=step, row (lane>>4)*4+reg=gate
    const int mst = lane & 15;
    const int mq  = (lane >> 4) * 4;
    const int mxr = (mst & 7) << 2;

    // prologue: stage chunk 0 (write -> read in-order within the wave),
    // compute gx[0], prefetch chunk 1. No barriers: single-wave block.
    {
        float4 f0 = *(const float4*)xp;
        *(v4h*)(xsb + sl * FF + wl * 4) =
            (v4h){(f16)f0.x, (f16)f0.y, (f16)f0.z, (f16)f0.w};
    }
    xp += dstep;
    {
        v8h bx0 = {(f16)0,(f16)0,(f16)0,(f16)0,(f16)0,(f16)0,(f16)0,(f16)0};
        if (lane < 32)
            bx0 = *(const v8h*)(xsb + (lane & 15) * FF + (lane >> 4) * 8);
        float* gw = gxb + mst * NG;
#pragma unroll
        for (int T = 0; T < 8; ++T) {
            f32x4 acc = __builtin_amdgcn_mfma_f32_16x16x32_f16(
                awx[T], bx0, (f32x4){0.f, 0.f, 0.f, 0.f}, 0, 0, 0);
            *(f32x4*)(gw + ((mq + T * 16) ^ mxr)) = acc;
        }
    }
    float4 nf = *(const float4*)xp;   // chunk 1
    xp += dstep;

    float c = 0.0f, h = 0.0f;
    int hs[HH / 2];                   // packed f16 h-pairs (wave-uniform)
#pragma unroll
    for (int m = 0; m < HH / 2; ++m) hs[m] = 0;

    for (int ci = 0; ci < NC; ++ci) {
        const int bufc = ci & 1;
        const int bufn = bufc ^ 1;
        const bool more = (ci + 1 < NC);

        // chunk top: stage next x into LDS, read bx (ready by step ~2),
        // issue the next global prefetch (covered by ~28 steps of compute)
        v8h bx = {(f16)0,(f16)0,(f16)0,(f16)0,(f16)0,(f16)0,(f16)0,(f16)0};
        if (more) {
            *(v4h*)(xsb + bufn * (CH * FF) + sl * FF + wl * 4) =
                (v4h){(f16)nf.x, (f16)nf.y, (f16)nf.z, (f16)nf.w};
            if (lane < 32)
                bx = *(const v8h*)(xsb + bufn * (CH * FF) + (lane & 15) * FF + (lane >> 4) * 8);
            if (ci + 2 < NC) { nf = *(const float4*)xp; xp += dstep; }
        }

        const float* gxc = gxb + bufc * (CH * NG);

#pragma unroll
        for (int tt = 0; tt < 12; ++tt) LSTEP(tt)

        // deferred staging compute: 8 MFMA + gxb writes for chunk ci+1.
        // Results are consumed >=4 steps later; steps 0..11's gx reads
        // were not blocked by this write train.
        if (more) {
            float* gw = gxb + bufn * (CH * NG) + mst * NG;
#pragma unroll
            for (int T = 0; T < 8; ++T) {
                f32x4 acc = __builtin_amdgcn_mfma_f32_16x16x32_f16(
                    awx[T], bx, (f32x4){0.f, 0.f, 0.f, 0.f}, 0, 0, 0);
                *(f32x4*)(gw + ((mq + T * 16) ^ mxr)) = acc;
            }
        }

#pragma unroll
        for (int tt = 12; tt < CH; ++tt) LSTEP(tt)
    }

    if (hi) hidden[(size_t)bb * 64 + dir * HH + kk] = h;
}

// FC1 + per-block partial of FC2. Grid: 32 blocks x 256 threads.
__global__ __launch_bounds__(256)
void fc_partial_kernel(const float* __restrict__ hidden,
                       const float* __restrict__ Wfh, const float* __restrict__ bfh,
                       const float* __restrict__ Wfo,
                       float* __restrict__ partials)
{
    __shared__ float wsh[OO * 64];
    const int tid = threadIdx.x;
    for (int i = tid; i < OO * 64; i += 256) wsh[i] = Wfh[i];
    __syncthreads();

    const int r   = tid >> 3;
    const int o   = tid & 7;
    const int row = blockIdx.x * 32 + r;

    const float* hrow = hidden + (size_t)row * 64;
    float acc = bfh[o];
#pragma unroll
    for (int j = 0; j < 64; ++j) acc += hrow[j] * wsh[o * 64 + j];

    const int fidx = blockIdx.x * 256 + tid;

    float pv[OO];
#pragma unroll
    for (int o2 = 0; o2 < OO; ++o2) pv[o2] = Wfo[(size_t)o2 * (BB * OO) + fidx] * acc;

    __shared__ float red[4][OO];
#pragma unroll
    for (int o2 = 0; o2 < OO; ++o2) {
        float v = pv[o2];
        for (int off = 32; off > 0; off >>= 1) v += __shfl_down(v, off);
        if ((tid & 63) == 0) red[tid >> 6][o2] = v;
    }
    __syncthreads();
    if (tid < OO) {
        partials[blockIdx.x * OO + tid] =
            red[0][tid] + red[1][tid] + red[2][tid] + red[3][tid];
    }
}

__global__ void finalize_kernel(const float* __restrict__ partials,
                                const float* __restrict__ bfo,
                                float* __restrict__ out)
{
    __shared__ float s[OO];
    const int tid = threadIdx.x;
    if (tid < OO) {
        float acc = bfo[tid];
        for (int b = 0; b < 32; ++b) acc += partials[b * OO + tid];
        s[tid] = acc;
    }
    __syncthreads();
    if (tid == 0) {
        float m = s[0];
        for (int i = 1; i < OO; ++i) m = fmaxf(m, s[i]);
        float e[OO], sum = 0.0f;
        for (int i = 0; i < OO; ++i) { e[i] = expf(s[i] - m); sum += e[i]; }
        for (int i = 0; i < OO; ++i) out[i] = e[i] / sum;
    }
}

extern "C" void kernel_launch(void* const* d_in, const int* in_sizes, int n_in,
                              void* d_out, int out_size, void* d_ws, size_t ws_size,
                              hipStream_t stream) {
    const float* x     = (const float*)d_in[0];
    const float* Wih_f = (const float*)d_in[1];
    const float* Whh_f = (const float*)d_in[2];
    const float* b_f   = (const float*)d_in[3];
    const float* Wih_b = (const float*)d_in[4];
    const float* Whh_b = (const float*)d_in[5];
    const float* b_b   = (const float*)d_in[6];
    const float* Wfh   = (const float*)d_in[7];
    const float* bfh   = (const float*)d_in[8];
    const float* Wfo   = (const float*)d_in[9];
    const float* bfo   = (const float*)d_in[10];

    float* hidden   = (float*)d_ws;
    float* partials = hidden + (size_t)BB * 64;

    lstm_seq_kernel<<<2 * BB, 64, 0, stream>>>(x, Wih_f, Whh_f, b_f,
                                               Wih_b, Whh_b, b_b, hidden);
    fc_partial_kernel<<<32, 256, 0, stream>>>(hidden, Wfh, bfh, Wfo, partials);
    finalize_kernel<<<1, 64, 0, stream>>>(partials, bfo, (float*)d_out);
}